// Round 6
// baseline (143.083 us; speedup 1.0000x reference)
//
#include <hip/hip_runtime.h>

#define Wd 640
#define Hd 512
#define NB 32
#define TW 64
#define TH 16
#define RR 4
#define SW 72                      // LDS row stride (dwords); staging byte = 16*f magic
constexpr int TILES_X = Wd / TW;   // 10
constexpr int TILES_Y = Hd / TH;   // 32
constexpr int PLANE  = (TH + RR) * SW;   // 1440 dwords per plane
constexpr float EPSC = 0.5f;

// ---------------- Kernel A: disparity warp (bilinear along x) ----------------
__global__ __launch_bounds__(256)
void warp_kernel(const float* __restrict__ disp, const float* __restrict__ pattern,
                 float* __restrict__ proj)
{
    int gid = blockIdx.x * 256 + threadIdx.x;   // one thread per 4 px
    int n = gid * 4;
    float4 d4 = *(const float4*)(disp + n);
    int u = n % Wd;
    int rowbase = ((n / Wd) % Hd) * Wd;
    float dv[4] = {d4.x, d4.y, d4.z, d4.w};
    #pragma unroll
    for (int j = 0; j < 4; ++j) {
        float x = (float)(u + j) - dv[j];
        x = fminf(fmaxf(x, 0.f), (float)(Wd - 1));
        float x0 = floorf(x);
        float w = x - x0;
        int i0 = (int)x0;
        int i1 = min(i0 + 1, Wd - 1);
        float g0 = pattern[rowbase + i0];
        float g1 = pattern[rowbase + i1];
        proj[n + j] = fmaf(w, g1 - g0, g0);
    }
}

// ---------------- census numerator/denominator (d-form, no divide) ----------------
// c(x)=x/(eps+|x|);  ca-cb = (da*d2 - db*d1)/(d1*d2),  d1=eps+|da|, d2=eps+|db|
__device__ __forceinline__ void census_ne(float na, float nb, float ac, float bc,
                                          float& n, float& e)
{
    float da = na - ac;
    float db = nb - bc;
    float d1 = EPSC + fabsf(da);
    float d2 = EPSC + fabsf(db);
    n = fmaf(da, d2, -(db * d1));
    e = d1 * d2;                        // in [0.25, 2.25]
}

// Sum of 4 terms with ONE rcp
__device__ __forceinline__ float comb4(float n1, float e1, float n2, float e2,
                                       float n3, float e3, float n4, float e4)
{
    float e12 = e1 * e2, e34 = e3 * e4;
    float s12 = fmaf(fabsf(n2), e1, fabsf(n1) * e2);
    float s34 = fmaf(fabsf(n4), e3, fabsf(n3) * e4);
    float t   = fmaf(s34, e12, s12 * e34);
    return t * __builtin_amdgcn_rcpf(e12 * e34);
}

// window load for strip row DH: a_i/b_i = LDS col (lane + i), i.e. image col x+i-4
#define WLOAD(DH) \
    a0=p0[(DH)*SW+0]; a1=p0[(DH)*SW+1]; a2=p0[(DH)*SW+2]; a3=p0[(DH)*SW+3]; \
    a4=p0[(DH)*SW+4]; a5=p0[(DH)*SW+5]; a6=p0[(DH)*SW+6]; a7=p0[(DH)*SW+7]; \
    a8=p0[(DH)*SW+8]; \
    b0=p1[(DH)*SW+0]; b1=p1[(DH)*SW+1]; b2=p1[(DH)*SW+2]; b3=p1[(DH)*SW+3]; \
    b4=p1[(DH)*SW+4]; b5=p1[(DH)*SW+5]; b6=p1[(DH)*SW+6]; b7=p1[(DH)*SW+7]; \
    b8=p1[(DH)*SW+8];

// center row of pixel P: capture centers + right-half terms (d=1..4)
#define CENTERRT(P) { \
    cA##P = a4; cB##P = b4; \
    float n0,e0,n1,e1,n2,e2,n3,e3; \
    census_ne(a5,b5,a4,b4,n0,e0); \
    census_ne(a6,b6,a4,b4,n1,e1); \
    census_ne(a7,b7,a4,b4,n2,e2); \
    census_ne(a8,b8,a4,b4,n3,e3); \
    if constexpr (EC) { n0*=mm[5]; n1*=mm[6]; n2*=mm[7]; n3*=mm[8]; } \
    acc##P += comb4(n0,e0,n1,e1,n2,e2,n3,e3); }

// full 9-wide row terms for pixel P from the current window
#define ROWP(P) { \
    float n0,e0,n1,e1,n2,e2,n3,e3,n4,e4,n5,e5,n6,e6,n7,e7,n8,e8; \
    census_ne(a0,b0,cA##P,cB##P,n0,e0); \
    census_ne(a1,b1,cA##P,cB##P,n1,e1); \
    census_ne(a2,b2,cA##P,cB##P,n2,e2); \
    census_ne(a3,b3,cA##P,cB##P,n3,e3); \
    census_ne(a4,b4,cA##P,cB##P,n4,e4); \
    census_ne(a5,b5,cA##P,cB##P,n5,e5); \
    census_ne(a6,b6,cA##P,cB##P,n6,e6); \
    census_ne(a7,b7,cA##P,cB##P,n7,e7); \
    census_ne(a8,b8,cA##P,cB##P,n8,e8); \
    if constexpr (EC) { n0*=mm[0]; n1*=mm[1]; n2*=mm[2]; n3*=mm[3]; \
                        n5*=mm[5]; n6*=mm[6]; n7*=mm[7]; n8*=mm[8]; } \
    acc##P += comb4(n0,e0,n1,e1,n2,e2,n3,e3); \
    acc##P += comb4(n5,e5,n6,e6,n7,e7,n8,e8); \
    acc##P += fabsf(n4) * __builtin_amdgcn_rcpf(e4); }

template<bool EC>
__device__ __forceinline__ float strip_sum(const float* p0, const float* p1,
                                           int gr0, int x)
{
    float mm[9];
    if constexpr (EC) {
        #pragma unroll
        for (int i = 0; i < 9; ++i)
            mm[i] = ((unsigned)(x + i - 4) < (unsigned)Wd) ? 1.f : 0.f;
    }
    float a0,a1,a2,a3,a4,a5,a6,a7,a8, b0,b1,b2,b3,b4,b5,b6,b7,b8;
    float cA0,cA1,cA2,cA3, cB0,cB1,cB2,cB3;
    float acc0=0.f, acc1=0.f, acc2=0.f, acc3=0.f;

    WLOAD(0) CENTERRT(0)
    WLOAD(1) CENTERRT(1) ROWP(0)
    WLOAD(2) CENTERRT(2) ROWP(0) ROWP(1)
    WLOAD(3) CENTERRT(3) ROWP(0) ROWP(1) ROWP(2)
    if (gr0 + 4 < Hd) { WLOAD(4) ROWP(0) ROWP(1) ROWP(2) ROWP(3) }
    if (gr0 + 5 < Hd) { WLOAD(5) ROWP(1) ROWP(2) ROWP(3) }
    if (gr0 + 6 < Hd) { WLOAD(6) ROWP(2) ROWP(3) }
    if (gr0 + 7 < Hd) { WLOAD(7) ROWP(3) }
    return (acc0 + acc1) + (acc2 + acc3);
}

// ---------------- Kernel B: half-space census, column-strip mapping ----------------
// lane owns column x = tU*64 + (tid&63); warp w owns rows v0+4w .. v0+4w+3.
// All LDS reads: consecutive lanes -> consecutive dwords (conflict-free, m136).
__global__ __launch_bounds__(256)
void census_kernel(const float* __restrict__ proj, const float* __restrict__ im,
                   float* __restrict__ partial)
{
    __shared__ float lds[2 * PLANE];            // [proj | im], rows v0..v0+19, cols u0g..+71

    const int tU = blockIdx.x, tV = blockIdx.y, b = blockIdx.z;
    const int tid = threadIdx.x;
    const float* pb = proj + (size_t)b * (Hd * Wd);
    const float* ib = im   + (size_t)b * (Hd * Wd);
    const int v0  = tV * TH;
    const int u0g = tU * TW - RR;               // global col of LDS col 0

    const bool edgeC = (tU == 0) | (tU == TILES_X - 1);
    const bool edgeR = (tV == TILES_Y - 1);

    if (!edgeC && !edgeR) {
        // fast staging: byte offset = 16*f -> consecutive lanes, consecutive granules
        const float* pbase = pb + v0 * Wd + u0g;
        const float* ibase = ib + v0 * Wd + u0g;
        for (int f = tid; f < (TH + RR) * 18; f += 256) {   // 360 float4s
            int r = f / 18;
            int c = (f - 18 * r) * 4;
            *(float4*)&lds[r * SW + c]         = *(const float4*)(pbase + r * Wd + c);
            *(float4*)&lds[PLANE + r * SW + c] = *(const float4*)(ibase + r * Wd + c);
        }
    } else {
        for (int idx = tid; idx < PLANE; idx += 256) {
            int r = idx / SW;
            int c = idx - r * SW;
            int gv = min(v0 + r, Hd - 1);
            int gu = min(max(u0g + c, 0), Wd - 1);
            int off = gv * Wd + gu;
            lds[idx]         = pb[off];
            lds[PLANE + idx] = ib[off];
        }
    }
    __syncthreads();

    const int lane = tid & 63;                  // column within tile
    const int w    = tid >> 6;                  // strip index (4 rows each)
    const int x    = tU * TW + lane;            // global column
    const int gr0  = v0 + 4 * w;                // global row of strip pixel 0
    const float* p0 = lds + (4 * w) * SW + lane;        // A-plane window base
    const float* p1 = p0 + PLANE;                       // B-plane

    float acc = edgeC ? strip_sum<true >(p0, p1, gr0, x)
                      : strip_sum<false>(p0, p1, gr0, x);

    // block reduction -> one partial per block (deterministic)
    #pragma unroll
    for (int o = 32; o; o >>= 1) acc += __shfl_down(acc, o);
    __shared__ float wsum[4];
    if (lane == 0) wsum[w] = acc;
    __syncthreads();
    if (tid == 0) {
        float s = wsum[0] + wsum[1] + wsum[2] + wsum[3];
        partial[((int)blockIdx.z * gridDim.y + blockIdx.y) * gridDim.x + blockIdx.x] = s;
    }
}

// ---------------- Kernel C: final deterministic reduce ----------------
__global__ __launch_bounds__(1024)
void final_reduce(const float* __restrict__ partial, float* __restrict__ out)
{
    const int n = NB * TILES_Y * TILES_X;       // 10240
    double s = 0.0;
    for (int i = threadIdx.x; i < n; i += 1024) s += (double)partial[i];
    __shared__ double sm[1024];
    sm[threadIdx.x] = s;
    __syncthreads();
    for (int st = 512; st; st >>= 1) {
        if (threadIdx.x < st) sm[threadIdx.x] += sm[threadIdx.x + st];
        __syncthreads();
    }
    if (threadIdx.x == 0) {
        // val = 2 * S_half / (81 * B*H*W)   (half-space symmetry doubling)
        out[0] = (float)(sm[0] * (2.0 / (81.0 * (double)NB * Hd * Wd)));
    }
}

extern "C" void kernel_launch(void* const* d_in, const int* in_sizes, int n_in,
                              void* d_out, int out_size, void* d_ws, size_t ws_size,
                              hipStream_t stream)
{
    const float* disp    = (const float*)d_in[0];
    const float* im      = (const float*)d_in[1];
    const float* pattern = (const float*)d_in[2];
    float* out  = (float*)d_out;
    float* proj = out + 1;                      // output 1: pattern_proj
    float* partial = (float*)d_ws;              // 10240 floats scratch

    const int npx = NB * Hd * Wd;
    warp_kernel<<<npx / (256 * 4), 256, 0, stream>>>(disp, pattern, proj);

    dim3 grid(TILES_X, TILES_Y, NB);
    census_kernel<<<grid, 256, 0, stream>>>(proj, im, partial);

    final_reduce<<<1, 1024, 0, stream>>>(partial, out);
}